// Round 6
// baseline (505.281 us; speedup 1.0000x reference)
//
#include <hip/hip_runtime.h>

#define NVOX 20000
#define MPTS 64
#define CIN  10
#define NM   (NVOX*MPTS)      // 1,280,000
#define EPSBN 1e-3f

// ws param layout (float offsets) — only 512 floats used
#define WS_SCALE0 0     // 64
#define WS_SHIFT0 64    // 64
#define WS_SCALE1 128   // 128
#define WS_SHIFT1 256   // 128

// d_out doubles as stream-ordered scratch for reduction partials.
#define NB0   1024      // stats0 blocks -> P0 partials [NB0][P0STR]
#define P0STR 72
#define NBP   2000      // k_pass blocks; 10 voxels each, exact
#define NITER 10

typedef short bf16x8 __attribute__((ext_vector_type(8)));
typedef float f32x4  __attribute__((ext_vector_type(4)));
typedef unsigned int u32x4 __attribute__((ext_vector_type(4)));

__device__ __forceinline__ unsigned short f2bf(float f) {
    union { float f; unsigned u; } v; v.f = f;
    unsigned r = v.u + 0x7FFFu + ((v.u >> 16) & 1u);   // RNE to bf16
    return (unsigned short)(r >> 16);
}
// HW packed f32x2 -> bf16x2 (no builtin on gfx950)
__device__ __forceinline__ unsigned cvtpk(float lo, float hi) {
    unsigned d;
    asm("v_cvt_pk_bf16_f32 %0, %1, %2" : "=v"(d) : "v"(lo), "v"(hi));
    return d;
}
// packed u16 max: valid max for ReLU'd (non-negative) bf16 bit patterns
__device__ __forceinline__ unsigned pkmax(unsigned a, unsigned b) {
    unsigned d;
    asm("v_pk_max_u16 %0, %1, %2" : "=v"(d) : "v"(a), "v"(b));
    return d;
}

// x-moment pass: Sx (10) + Sxx (55 packed) via per-block partials, NO atomics.
__global__ __launch_bounds__(256) void k_stats0(const float* __restrict__ x,
                                                float* __restrict__ p0) {
    __shared__ float sm[4][P0STR];
    float sx[CIN];
    float sxx[55];
#pragma unroll
    for (int i = 0; i < CIN; i++) sx[i] = 0.f;
#pragma unroll
    for (int k = 0; k < 55; k++) sxx[k] = 0.f;

    const int t = threadIdx.x;
    const int tid = blockIdx.x * 256 + t;

    for (int g = tid; g < NM / 2; g += NB0 * 256) {
        const float4* xp = (const float4*)(x + (size_t)g * 20);
        float4 a = xp[0], b = xp[1], c = xp[2], d = xp[3], e = xp[4];
        float v0[CIN] = {a.x, a.y, a.z, a.w, b.x, b.y, b.z, b.w, c.x, c.y};
        float v1[CIN] = {c.z, c.w, d.x, d.y, d.z, d.w, e.x, e.y, e.z, e.w};
#pragma unroll
        for (int i = 0; i < CIN; i++) sx[i] += v0[i] + v1[i];
#pragma unroll
        for (int i = 0; i < CIN; i++)
#pragma unroll
            for (int j = 0; j <= i; j++)
                sxx[i * (i + 1) / 2 + j] += v0[i] * v0[j] + v1[i] * v1[j];
    }

    const int l = t & 63, w = t >> 6;
#pragma unroll
    for (int i = 0; i < CIN; i++) {
        float v = sx[i];
#pragma unroll
        for (int off = 32; off; off >>= 1) v += __shfl_xor(v, off, 64);
        if (l == 0) sm[w][i] = v;
    }
#pragma unroll
    for (int k = 0; k < 55; k++) {
        float v = sxx[k];
#pragma unroll
        for (int off = 32; off; off >>= 1) v += __shfl_xor(v, off, 64);
        if (l == 0) sm[w][10 + k] = v;
    }
    __syncthreads();
    if (t < 65)
        p0[blockIdx.x * P0STR + t] = sm[0][t] + sm[1][t] + sm[2][t] + sm[3][t];
}

__global__ void k_finalize0(const float* __restrict__ p0, float* __restrict__ ws,
                            const float* __restrict__ w0,
                            const float* __restrict__ gamma0, const float* __restrict__ beta0) {
    __shared__ float s[P0STR];
    const int t = threadIdx.x;
    if (t < 65) {
        float acc = 0.f;
#pragma unroll 8
        for (int r = 0; r < NB0; r++) acc += p0[r * P0STR + t];
        s[t] = acc;
    }
    __syncthreads();
    if (t < 64) {
        float w[CIN];
#pragma unroll
        for (int i = 0; i < CIN; i++) w[i] = w0[t * CIN + i];
        float m = 0.f;
#pragma unroll
        for (int i = 0; i < CIN; i++) m += w[i] * s[i];
        m *= (1.f / NM);
        float q = 0.f;
#pragma unroll
        for (int i = 0; i < CIN; i++)
#pragma unroll
            for (int j = 0; j <= i; j++)
                q += ((i == j) ? 1.f : 2.f) * w[i] * w[j] * s[10 + i * (i + 1) / 2 + j];
        q *= (1.f / NM);
        float var = q - m * m;
        float scale = gamma0[t] * rsqrtf(var + EPSBN);
        ws[WS_SCALE0 + t] = scale;
        ws[WS_SHIFT0 + t] = beta0[t] - m * scale;
    }
}

__global__ void k_finalize1(const float* __restrict__ p1, float* __restrict__ ws,
                            const float* __restrict__ gamma1, const float* __restrict__ beta1) {
    __shared__ float sm[2][4];
    const int c = blockIdx.x;
    const int t = threadIdx.x, l = t & 63, w = t >> 6;
    float s = 0.f, qq = 0.f;
    for (int r = t; r < NBP; r += 256) {
        s  += p1[(size_t)r * 256 + c];
        qq += p1[(size_t)r * 256 + 128 + c];
    }
#pragma unroll
    for (int off = 32; off; off >>= 1) { s += __shfl_xor(s, off, 64); qq += __shfl_xor(qq, off, 64); }
    if (l == 0) { sm[0][w] = s; sm[1][w] = qq; }
    __syncthreads();
    if (t == 0) {
        float S = sm[0][0] + sm[0][1] + sm[0][2] + sm[0][3];
        float Q = sm[1][0] + sm[1][1] + sm[1][2] + sm[1][3];
        float m = S * (1.f / NM);
        float var = Q * (1.f / NM) - m * m;
        float scale = gamma1[c] * rsqrtf(var + EPSBN);
        ws[WS_SCALE1 + c] = scale;
        ws[WS_SHIFT1 + c] = beta1[c] - m * scale;
    }
}

// Own-points restructure: 4 waves, wave w owns points 16w..16w+15 end-to-end.
// L0 B-frag loads straight from global (lane (lr,lg) needs exactly x[16w+lr][8lg..+7];
// lg>=2 rows are the K-pad) — no xB, no staging barrier. z lives in wave-PRIVATE zB rows
// (write 4xb64, read 2xb128 transpose for the L1 A-frag; DS in-order per wave, no barrier).
// L1: wave computes its 16 points x all 128 cols; W1 frags for all 8 njl in registers.
// Cross-wave: aggP (concat max, double-buffered) and vmP (FINAL max-over-points,
// double-buffered, folded for voxel n-1 after voxel n's barrier) -> ONE barrier/voxel.
template <bool STATS>
__global__ __launch_bounds__(256, 2) void k_pass(const float* __restrict__ x,
                                                 const float* __restrict__ w0,
                                                 const float* __restrict__ w1,
                                                 const float* __restrict__ ws,
                                                 float* __restrict__ pout) {
    __shared__ unsigned short zB[MPTS * 72];      // 9216 B  (wave-private row groups)
    __shared__ unsigned short aggP[2 * 4 * 64];   // 1024 B  (double-buffered)
    __shared__ float vmP[2 * 4 * 132];            // 4224 B  (FINAL partial col-max)
    __shared__ float pbuf[4 * 256];               // 4096 B  (STATS staging)

    const int t  = threadIdx.x;
    const int l  = t & 63;
    const int w  = t >> 6;
    const int lr = l & 15;
    const int lg = l >> 4;
    const int prow = 16 * w + lr;                 // this lane's point row

    // W0 fragments, BN0 folded: A rows ch = 16mi+lr, k = 8lg+j (k10 = shift, rest 0)
    bf16x8 w0f[4];
#pragma unroll
    for (int mi = 0; mi < 4; mi++) {
        int ch = 16 * mi + lr;
        float sc = ws[WS_SCALE0 + ch], sh = ws[WS_SHIFT0 + ch];
        bf16x8 f;
#pragma unroll
        for (int j = 0; j < 8; j++) {
            int k = 8 * lg + j;
            float v = (k < CIN) ? sc * w0[ch * CIN + k] : (k == CIN ? sh : 0.f);
            f[j] = (short)f2bf(v);
        }
        w0f[mi] = f;
    }

    // W1 fragments for ALL 8 col-groups: B cols o = 16njl+lr, k = 32ks+8lg+j
    bf16x8 wfrag[8][4];
#pragma unroll
    for (int njl = 0; njl < 8; njl++) {
        const float* wrow = w1 + (16 * njl + lr) * 128;
#pragma unroll
        for (int ks = 0; ks < 4; ks++) {
            float4 a = *(const float4*)(wrow + 32 * ks + 8 * lg);
            float4 b = *(const float4*)(wrow + 32 * ks + 8 * lg + 4);
            bf16x8 f;
            f[0] = (short)f2bf(a.x); f[1] = (short)f2bf(a.y);
            f[2] = (short)f2bf(a.z); f[3] = (short)f2bf(a.w);
            f[4] = (short)f2bf(b.x); f[5] = (short)f2bf(b.y);
            f[6] = (short)f2bf(b.z); f[7] = (short)f2bf(b.w);
            wfrag[njl][ks] = f;
        }
    }

    float sc1[8], sh1[8];
    if (!STATS) {
#pragma unroll
        for (int njl = 0; njl < 8; njl++) {
            int col = 16 * njl + lr;
            sc1[njl] = ws[WS_SCALE1 + col];
            sh1[njl] = ws[WS_SHIFT1 + col];
        }
    }
    float as_[8], aq[8];
    if (STATS) {
#pragma unroll
        for (int njl = 0; njl < 8; njl++) { as_[njl] = 0.f; aq[njl] = 0.f; }
    }

    // prologue: prefetch voxel bid's x (only lg<2 lanes carry data)
    float2 pfA, pfB, pfC, pfD;
    {
        const float* xr = x + (size_t)blockIdx.x * 640 + prow * CIN;
        if (lg == 0) {
            pfA = *(const float2*)(xr + 0); pfB = *(const float2*)(xr + 2);
            pfC = *(const float2*)(xr + 4); pfD = *(const float2*)(xr + 6);
        } else if (lg == 1) {
            pfA = *(const float2*)(xr + 8);
        }
    }

    for (int k = 0; k < NITER; k++) {
        const int n = blockIdx.x + k * NBP;
        const int buf = k & 1;

        // ---- convert prefetch -> L0 B-fragment ----
        u32x4 bxu = {0u, 0u, 0u, 0u};
        if (lg == 0) {
            bxu[0] = cvtpk(pfA.x, pfA.y); bxu[1] = cvtpk(pfB.x, pfB.y);
            bxu[2] = cvtpk(pfC.x, pfC.y); bxu[3] = cvtpk(pfD.x, pfD.y);
        } else if (lg == 1) {
            bxu[0] = cvtpk(pfA.x, pfA.y);
            bxu[1] = 0x00003F80u;          // k10 = 1.0 (shift lane), k11 = 0
        }
        bf16x8 bx = __builtin_bit_cast(bf16x8, bxu);

        // ---- issue prefetch for voxel n+NBP ----
        if (k < NITER - 1) {
            const float* xr = x + (size_t)(n + NBP) * 640 + prow * CIN;
            if (lg == 0) {
                pfA = *(const float2*)(xr + 0); pfB = *(const float2*)(xr + 2);
                pfC = *(const float2*)(xr + 4); pfD = *(const float2*)(xr + 6);
            } else if (lg == 1) {
                pfA = *(const float2*)(xr + 8);
            }
        }

        // ---- L0: 4 MFMA -> z[ch][own p] in regs -> ReLU+pack -> wave-private zB ----
#pragma unroll
        for (int mi = 0; mi < 4; mi++) {
            f32x4 zz = {0.f, 0.f, 0.f, 0.f};
            f32x4 a0 = __builtin_amdgcn_mfma_f32_16x16x32_bf16(w0f[mi], bx, zz, 0, 0, 0);
            uint2 dd = { cvtpk(fmaxf(a0[0], 0.f), fmaxf(a0[1], 0.f)),
                         cvtpk(fmaxf(a0[2], 0.f), fmaxf(a0[3], 0.f)) };
            *(uint2*)&zB[prow * 72 + 16 * mi + 4 * lg] = dd;   // ch 16mi+4lg..+3
        }

        // ---- L1 A-frag: transpose read of own zB rows (wave-local, in-order DS) ----
        bf16x8 af0 = *(const bf16x8*)&zB[prow * 72 + 8 * lg];        // ch 8lg..+7
        bf16x8 af1 = *(const bf16x8*)&zB[prow * 72 + 32 + 8 * lg];   // ch 32+8lg..+7

        // ---- agg partial: wave-local max over own 16 rows (packed bf16) ----
        {
            int cs = l & 7;
            int pa = 16 * w + 2 * (l >> 3);
            u32x4 ra = *(const u32x4*)&zB[pa * 72 + cs * 8];
            u32x4 rb = *(const u32x4*)&zB[(pa + 1) * 72 + cs * 8];
            u32x4 m;
#pragma unroll
            for (int k2 = 0; k2 < 4; k2++) m[k2] = pkmax(ra[k2], rb[k2]);
#pragma unroll
            for (int off = 8; off <= 32; off <<= 1)
#pragma unroll
                for (int k2 = 0; k2 < 4; k2++) m[k2] = pkmax(m[k2], __shfl_xor(m[k2], off));
            if (l < 8) *(u32x4*)&aggP[(buf * 4 + w) * 64 + l * 8] = m;
        }

        asm volatile("s_waitcnt lgkmcnt(0)" ::: "memory");
        __builtin_amdgcn_s_barrier();            // aggP[buf] ready; vmP[buf^1] complete

        // ---- FINAL: fold+store voxel n-NBP's output (pipelined epilogue) ----
        if (!STATS && k > 0) {
            if (l < 32) {
                int pb = buf ^ 1;
                int o = 32 * w + l;
                float v0 = vmP[(pb * 4 + 0) * 132 + o];
                float v1 = vmP[(pb * 4 + 1) * 132 + o];
                float v2 = vmP[(pb * 4 + 2) * 132 + o];
                float v3 = vmP[(pb * 4 + 3) * 132 + o];
                pout[(size_t)(n - NBP) * 128 + o] = fmaxf(fmaxf(v0, v1), fmaxf(v2, v3));
            }
        }

        // ---- gfrag: 4-way cross-wave fold of agg partials ----
        bf16x8 gf[2];
#pragma unroll
        for (int ks = 0; ks < 2; ks++) {
            int sl = (4 * ks + lg) * 8;
            u32x4 g = *(const u32x4*)&aggP[(buf * 4 + 0) * 64 + sl];
#pragma unroll
            for (int wv = 1; wv < 4; wv++) {
                u32x4 h2 = *(const u32x4*)&aggP[(buf * 4 + wv) * 64 + sl];
#pragma unroll
                for (int k2 = 0; k2 < 4; k2++) g[k2] = pkmax(g[k2], h2[k2]);
            }
            gf[ks] = __builtin_bit_cast(bf16x8, g);
        }

        // ---- L1: own 16 points x 128 cols; 8 independent 4-MFMA chains ----
#pragma unroll
        for (int njl = 0; njl < 8; njl++) {
            f32x4 acc = {0.f, 0.f, 0.f, 0.f};
            acc = __builtin_amdgcn_mfma_f32_16x16x32_bf16(af0, wfrag[njl][0], acc, 0, 0, 0);
            acc = __builtin_amdgcn_mfma_f32_16x16x32_bf16(af1, wfrag[njl][1], acc, 0, 0, 0);
            acc = __builtin_amdgcn_mfma_f32_16x16x32_bf16(gf[0], wfrag[njl][2], acc, 0, 0, 0);
            acc = __builtin_amdgcn_mfma_f32_16x16x32_bf16(gf[1], wfrag[njl][3], acc, 0, 0, 0);
            if (STATS) {
                as_[njl] += (acc[0] + acc[1]) + (acc[2] + acc[3]);
                aq[njl]  += (acc[0] * acc[0] + acc[1] * acc[1]) +
                            (acc[2] * acc[2] + acc[3] * acc[3]);
            } else {
                float v0 = fmaxf(fmaf(acc[0], sc1[njl], sh1[njl]), 0.f);
                float v1 = fmaxf(fmaf(acc[1], sc1[njl], sh1[njl]), 0.f);
                float v2 = fmaxf(fmaf(acc[2], sc1[njl], sh1[njl]), 0.f);
                float v3 = fmaxf(fmaf(acc[3], sc1[njl], sh1[njl]), 0.f);
                float m = fmaxf(fmaxf(v0, v1), fmaxf(v2, v3));
                m = fmaxf(m, __shfl_xor(m, 16));
                m = fmaxf(m, __shfl_xor(m, 32));
                if (l < 16) vmP[(buf * 4 + w) * 132 + njl * 16 + lr] = m;
            }
        }
    }

    if (!STATS) {
        // drain: fold last voxel (k = NITER-1, buf = (NITER-1)&1)
        asm volatile("s_waitcnt lgkmcnt(0)" ::: "memory");
        __builtin_amdgcn_s_barrier();
        if (l < 32) {
            int pb = (NITER - 1) & 1;
            int o = 32 * w + l;
            int n = blockIdx.x + (NITER - 1) * NBP;
            float v0 = vmP[(pb * 4 + 0) * 132 + o];
            float v1 = vmP[(pb * 4 + 1) * 132 + o];
            float v2 = vmP[(pb * 4 + 2) * 132 + o];
            float v3 = vmP[(pb * 4 + 3) * 132 + o];
            pout[(size_t)n * 128 + o] = fmaxf(fmaxf(v0, v1), fmaxf(v2, v3));
        }
    } else {
        // stats epilogue: reduce over rows (lg'), stage per wave, one coalesced store
#pragma unroll
        for (int njl = 0; njl < 8; njl++) {
            float s = as_[njl];
            s += __shfl_xor(s, 16); s += __shfl_xor(s, 32);
            float qv = aq[njl];
            qv += __shfl_xor(qv, 16); qv += __shfl_xor(qv, 32);
            if (l < 16) {
                pbuf[w * 256 + njl * 16 + lr] = s;
                pbuf[w * 256 + 128 + njl * 16 + lr] = qv;
            }
        }
        __syncthreads();
        float tot = pbuf[t] + pbuf[256 + t] + pbuf[512 + t] + pbuf[768 + t];
        pout[(size_t)blockIdx.x * 256 + t] = tot;
    }
}

extern "C" void kernel_launch(void* const* d_in, const int* in_sizes, int n_in,
                              void* d_out, int out_size, void* d_ws, size_t ws_size,
                              hipStream_t stream) {
    (void)in_sizes; (void)n_in; (void)out_size; (void)ws_size;
    const float* x      = (const float*)d_in[0];
    const float* W0     = (const float*)d_in[1];
    const float* gamma0 = (const float*)d_in[2];
    const float* beta0  = (const float*)d_in[3];
    const float* W1     = (const float*)d_in[4];
    const float* gamma1 = (const float*)d_in[5];
    const float* beta1  = (const float*)d_in[6];
    float* out = (float*)d_out;
    float* ws  = (float*)d_ws;

    k_stats0<<<NB0, 256, 0, stream>>>(x, out);                       // partials -> out
    k_finalize0<<<1, 256, 0, stream>>>(out, ws, W0, gamma0, beta0);
    k_pass<true><<<NBP, 256, 0, stream>>>(x, W0, W1, ws, out);       // partials -> out
    k_finalize1<<<128, 256, 0, stream>>>(out, ws, gamma1, beta1);
    k_pass<false><<<NBP, 256, 0, stream>>>(x, W0, W1, ws, out);      // final output
}

// Round 7
// 250.150 us; speedup vs baseline: 2.0199x; 2.0199x over previous
//
#include <hip/hip_runtime.h>

#define NVOX 20000
#define MPTS 64
#define CIN  10
#define NM   (NVOX*MPTS)      // 1,280,000
#define EPSBN 1e-3f

// ws param layout (float offsets) — only 512 floats used
#define WS_SCALE0 0     // 64
#define WS_SHIFT0 64    // 64
#define WS_SCALE1 128   // 128
#define WS_SHIFT1 256   // 128

// d_out doubles as stream-ordered scratch for reduction partials.
#define NB0   1024      // stats0 blocks -> P0 partials [NB0][P0STR]
#define P0STR 72
#define NBP   2000      // k_pass blocks; 2 streams x 5 iters = 10 voxels each
#define NITER 5

typedef short bf16x8 __attribute__((ext_vector_type(8)));
typedef float f32x4  __attribute__((ext_vector_type(4)));
typedef unsigned int u32x4 __attribute__((ext_vector_type(4)));

__device__ __forceinline__ unsigned short f2bf(float f) {
    union { float f; unsigned u; } v; v.f = f;
    unsigned r = v.u + 0x7FFFu + ((v.u >> 16) & 1u);   // RNE to bf16
    return (unsigned short)(r >> 16);
}
// HW packed f32x2 -> bf16x2 (no builtin on gfx950)
__device__ __forceinline__ unsigned cvtpk(float lo, float hi) {
    unsigned d;
    asm("v_cvt_pk_bf16_f32 %0, %1, %2" : "=v"(d) : "v"(lo), "v"(hi));
    return d;
}
// packed u16 max: valid max for ReLU'd (non-negative) bf16 bit patterns
__device__ __forceinline__ unsigned pkmax(unsigned a, unsigned b) {
    unsigned d;
    asm("v_pk_max_u16 %0, %1, %2" : "=v"(d) : "v"(a), "v"(b));
    return d;
}

// x-moment pass: Sx (10) + Sxx (55 packed) via per-block partials, NO atomics.
__global__ __launch_bounds__(256) void k_stats0(const float* __restrict__ x,
                                                float* __restrict__ p0) {
    __shared__ float sm[4][P0STR];
    float sx[CIN];
    float sxx[55];
#pragma unroll
    for (int i = 0; i < CIN; i++) sx[i] = 0.f;
#pragma unroll
    for (int k = 0; k < 55; k++) sxx[k] = 0.f;

    const int t = threadIdx.x;
    const int tid = blockIdx.x * 256 + t;

    for (int g = tid; g < NM / 2; g += NB0 * 256) {
        const float4* xp = (const float4*)(x + (size_t)g * 20);
        float4 a = xp[0], b = xp[1], c = xp[2], d = xp[3], e = xp[4];
        float v0[CIN] = {a.x, a.y, a.z, a.w, b.x, b.y, b.z, b.w, c.x, c.y};
        float v1[CIN] = {c.z, c.w, d.x, d.y, d.z, d.w, e.x, e.y, e.z, e.w};
#pragma unroll
        for (int i = 0; i < CIN; i++) sx[i] += v0[i] + v1[i];
#pragma unroll
        for (int i = 0; i < CIN; i++)
#pragma unroll
            for (int j = 0; j <= i; j++)
                sxx[i * (i + 1) / 2 + j] += v0[i] * v0[j] + v1[i] * v1[j];
    }

    const int l = t & 63, w = t >> 6;
#pragma unroll
    for (int i = 0; i < CIN; i++) {
        float v = sx[i];
#pragma unroll
        for (int off = 32; off; off >>= 1) v += __shfl_xor(v, off, 64);
        if (l == 0) sm[w][i] = v;
    }
#pragma unroll
    for (int k = 0; k < 55; k++) {
        float v = sxx[k];
#pragma unroll
        for (int off = 32; off; off >>= 1) v += __shfl_xor(v, off, 64);
        if (l == 0) sm[w][10 + k] = v;
    }
    __syncthreads();
    if (t < 65)
        p0[blockIdx.x * P0STR + t] = sm[0][t] + sm[1][t] + sm[2][t] + sm[3][t];
}

__global__ void k_finalize0(const float* __restrict__ p0, float* __restrict__ ws,
                            const float* __restrict__ w0,
                            const float* __restrict__ gamma0, const float* __restrict__ beta0) {
    __shared__ float s[P0STR];
    const int t = threadIdx.x;
    if (t < 65) {
        float acc = 0.f;
#pragma unroll 8
        for (int r = 0; r < NB0; r++) acc += p0[r * P0STR + t];
        s[t] = acc;
    }
    __syncthreads();
    if (t < 64) {
        float w[CIN];
#pragma unroll
        for (int i = 0; i < CIN; i++) w[i] = w0[t * CIN + i];
        float m = 0.f;
#pragma unroll
        for (int i = 0; i < CIN; i++) m += w[i] * s[i];
        m *= (1.f / NM);
        float q = 0.f;
#pragma unroll
        for (int i = 0; i < CIN; i++)
#pragma unroll
            for (int j = 0; j <= i; j++)
                q += ((i == j) ? 1.f : 2.f) * w[i] * w[j] * s[10 + i * (i + 1) / 2 + j];
        q *= (1.f / NM);
        float var = q - m * m;
        float scale = gamma0[t] * rsqrtf(var + EPSBN);
        ws[WS_SCALE0 + t] = scale;
        ws[WS_SHIFT0 + t] = beta0[t] - m * scale;
    }
}

__global__ void k_finalize1(const float* __restrict__ p1, float* __restrict__ ws,
                            const float* __restrict__ gamma1, const float* __restrict__ beta1) {
    __shared__ float sm[2][4];
    const int c = blockIdx.x;
    const int t = threadIdx.x, l = t & 63, w = t >> 6;
    float s = 0.f, qq = 0.f;
    for (int r = t; r < NBP; r += 256) {
        s  += p1[(size_t)r * 256 + c];
        qq += p1[(size_t)r * 256 + 128 + c];
    }
#pragma unroll
    for (int off = 32; off; off >>= 1) { s += __shfl_xor(s, off, 64); qq += __shfl_xor(qq, off, 64); }
    if (l == 0) { sm[0][w] = s; sm[1][w] = qq; }
    __syncthreads();
    if (t == 0) {
        float S = sm[0][0] + sm[0][1] + sm[0][2] + sm[0][3];
        float Q = sm[1][0] + sm[1][1] + sm[1][2] + sm[1][3];
        float m = S * (1.f / NM);
        float var = Q * (1.f / NM) - m * m;
        float scale = gamma1[c] * rsqrtf(var + EPSBN);
        ws[WS_SCALE1 + c] = scale;
        ws[WS_SHIFT1 + c] = beta1[c] - m * scale;
    }
}

// R5 structure (wave owns output cols 32w..32w+31 over all 64 points; wfrag[2][4]=32 VGPR)
// + two voxel streams per iteration + double-buffered zB/aggP -> ONE barrier per 2 voxels.
// L0 B-frag loads straight from global (no xB): lane (lr,lg) holds x[16w+lr][8lg..8lg+7],
// lg==1 carries k8,k9 + the BN-shift ones-column (k10), lg>=2 is K-pad zeros.
// zB rows are wave-private on write + agg readback (in-order DS per wave, verified R5/R6);
// cross-wave bz reads happen only after the barrier.
template <bool STATS>
__global__ __launch_bounds__(256) void k_pass(const float* __restrict__ x,
                                              const float* __restrict__ w0,
                                              const float* __restrict__ w1,
                                              const float* __restrict__ ws,
                                              float* __restrict__ pout) {
    __shared__ unsigned short zB[2][2][MPTS * 72];   // 36864 B  [buf][stream][p][ch]
    __shared__ unsigned short aggP[2][2][4 * 64];    // 2048 B
    __shared__ float pbuf[256];                      // 1024 B (STATS staging)

    const int t  = threadIdx.x;
    const int l  = t & 63;
    const int w  = t >> 6;
    const int lr = l & 15;
    const int lg = l >> 4;
    const int prow = 16 * w + lr;                    // this lane's point row

    // W0 fragments, BN0 folded: A rows ch = 16mi+lr, k = 8lg+j (k10 = shift, rest 0)
    bf16x8 w0f[4];
#pragma unroll
    for (int mi = 0; mi < 4; mi++) {
        int ch = 16 * mi + lr;
        float sc = ws[WS_SCALE0 + ch], sh = ws[WS_SHIFT0 + ch];
        bf16x8 f;
#pragma unroll
        for (int j = 0; j < 8; j++) {
            int k = 8 * lg + j;
            float v = (k < CIN) ? sc * w0[ch * CIN + k] : (k == CIN ? sh : 0.f);
            f[j] = (short)f2bf(v);
        }
        w0f[mi] = f;
    }

    // W1 fragments: B cols o = 32w+16njl+lr, k = 32ks+8lg+j
    bf16x8 wfrag[2][4];
#pragma unroll
    for (int njl = 0; njl < 2; njl++) {
        const float* wrow = w1 + (32 * w + 16 * njl + lr) * 128;
#pragma unroll
        for (int ks = 0; ks < 4; ks++) {
            float4 a = *(const float4*)(wrow + 32 * ks + 8 * lg);
            float4 b = *(const float4*)(wrow + 32 * ks + 8 * lg + 4);
            bf16x8 f;
            f[0] = (short)f2bf(a.x); f[1] = (short)f2bf(a.y);
            f[2] = (short)f2bf(a.z); f[3] = (short)f2bf(a.w);
            f[4] = (short)f2bf(b.x); f[5] = (short)f2bf(b.y);
            f[6] = (short)f2bf(b.z); f[7] = (short)f2bf(b.w);
            wfrag[njl][ks] = f;
        }
    }

    float sc1[2], sh1[2];
    if (!STATS) {
#pragma unroll
        for (int njl = 0; njl < 2; njl++) {
            int col = 32 * w + 16 * njl + lr;
            sc1[njl] = ws[WS_SCALE1 + col];
            sh1[njl] = ws[WS_SHIFT1 + col];
        }
    }
    float as_[2] = {0.f, 0.f}, aq[2] = {0.f, 0.f};

    auto PF = [&](int n, float2& r0, float2& r1, float2& r2, float2& r3) {
        const float* xr = x + (size_t)n * 640 + prow * CIN;
        if (lg == 0) {
            r0 = *(const float2*)(xr + 0); r1 = *(const float2*)(xr + 2);
            r2 = *(const float2*)(xr + 4); r3 = *(const float2*)(xr + 6);
        } else if (lg == 1) {
            r0 = *(const float2*)(xr + 8);
        }
    };
    auto MKBX = [&](float2 r0, float2 r1, float2 r2, float2 r3) -> bf16x8 {
        u32x4 u = {0u, 0u, 0u, 0u};
        if (lg == 0) {
            u[0] = cvtpk(r0.x, r0.y); u[1] = cvtpk(r1.x, r1.y);
            u[2] = cvtpk(r2.x, r2.y); u[3] = cvtpk(r3.x, r3.y);
        } else if (lg == 1) {
            u[0] = cvtpk(r0.x, r0.y);
            u[1] = 0x00003F80u;       // k10 = 1.0 (shift lane), k11 = 0
        }
        return __builtin_bit_cast(bf16x8, u);
    };
    auto L0 = [&](bf16x8 bx, int buf, int s) {
#pragma unroll
        for (int mi = 0; mi < 4; mi++) {
            f32x4 zz = {0.f, 0.f, 0.f, 0.f};
            f32x4 a0 = __builtin_amdgcn_mfma_f32_16x16x32_bf16(w0f[mi], bx, zz, 0, 0, 0);
            uint2 dd = { cvtpk(fmaxf(a0[0], 0.f), fmaxf(a0[1], 0.f)),
                         cvtpk(fmaxf(a0[2], 0.f), fmaxf(a0[3], 0.f)) };
            *(uint2*)&zB[buf][s][prow * 72 + 16 * mi + 4 * lg] = dd;  // ch 16mi+4lg..+3
        }
    };
    auto AGG = [&](int buf, int s) {
        int cs = l & 7;
        int pa = 16 * w + 2 * (l >> 3);
        u32x4 ra = *(const u32x4*)&zB[buf][s][pa * 72 + cs * 8];
        u32x4 rb = *(const u32x4*)&zB[buf][s][(pa + 1) * 72 + cs * 8];
        u32x4 m;
#pragma unroll
        for (int k2 = 0; k2 < 4; k2++) m[k2] = pkmax(ra[k2], rb[k2]);
#pragma unroll
        for (int off = 8; off <= 32; off <<= 1)
#pragma unroll
            for (int k2 = 0; k2 < 4; k2++) m[k2] = pkmax(m[k2], __shfl_xor(m[k2], off));
        if (l < 8) *(u32x4*)&aggP[buf][s][w * 64 + l * 8] = m;
    };
    auto CONSUME = [&](int buf, int s, int n) {
        bf16x8 bz[4][2];
#pragma unroll
        for (int pj = 0; pj < 4; pj++)
#pragma unroll
            for (int ks = 0; ks < 2; ks++)
                bz[pj][ks] = *(const bf16x8*)&zB[buf][s][(16 * pj + lr) * 72 + (4 * ks + lg) * 8];
        bf16x8 gf[2];
#pragma unroll
        for (int ks = 0; ks < 2; ks++) {
            int sl = (4 * ks + lg) * 8;
            u32x4 g = *(const u32x4*)&aggP[buf][s][sl];
#pragma unroll
            for (int wv = 1; wv < 4; wv++) {
                u32x4 h2 = *(const u32x4*)&aggP[buf][s][wv * 64 + sl];
#pragma unroll
                for (int k2 = 0; k2 < 4; k2++) g[k2] = pkmax(g[k2], h2[k2]);
            }
            gf[ks] = __builtin_bit_cast(bf16x8, g);
        }
        f32x4 dacc[2];
#pragma unroll
        for (int njl = 0; njl < 2; njl++) {
            f32x4 zz = {0.f, 0.f, 0.f, 0.f};
            zz = __builtin_amdgcn_mfma_f32_16x16x32_bf16(gf[0], wfrag[njl][2], zz, 0, 0, 0);
            dacc[njl] = __builtin_amdgcn_mfma_f32_16x16x32_bf16(gf[1], wfrag[njl][3], zz, 0, 0, 0);
        }
#pragma unroll
        for (int njl = 0; njl < 2; njl++) {
            float vm = 0.f;
#pragma unroll
            for (int mi = 0; mi < 4; mi++) {
                f32x4 acc = dacc[njl];
                acc = __builtin_amdgcn_mfma_f32_16x16x32_bf16(bz[mi][0], wfrag[njl][0], acc, 0, 0, 0);
                acc = __builtin_amdgcn_mfma_f32_16x16x32_bf16(bz[mi][1], wfrag[njl][1], acc, 0, 0, 0);
                if (STATS) {
#pragma unroll
                    for (int r = 0; r < 4; r++) { as_[njl] += acc[r]; aq[njl] += acc[r] * acc[r]; }
                } else {
#pragma unroll
                    for (int r = 0; r < 4; r++)
                        vm = fmaxf(vm, fmaxf(fmaf(acc[r], sc1[njl], sh1[njl]), 0.f));
                }
            }
            if (!STATS) {
                vm = fmaxf(vm, __shfl_xor(vm, 16));
                vm = fmaxf(vm, __shfl_xor(vm, 32));
                if (l < 16) pout[(size_t)n * 128 + 32 * w + 16 * njl + l] = vm;
            }
        }
    };

    // prologue: prefetch both streams' first voxels
    float2 aA0, aA1, aA2, aA3, aB0, aB1, aB2, aB3;
    PF(blockIdx.x, aA0, aA1, aA2, aA3);
    PF(blockIdx.x + NBP, aB0, aB1, aB2, aB3);

    for (int k = 0; k < NITER; k++) {
        const int buf = k & 1;
        const int nA = blockIdx.x + k * 2 * NBP;
        const int nB = nA + NBP;

        bf16x8 bxA = MKBX(aA0, aA1, aA2, aA3);
        bf16x8 bxB = MKBX(aB0, aB1, aB2, aB3);
        if (k < NITER - 1) {
            PF(nA + 2 * NBP, aA0, aA1, aA2, aA3);
            PF(nB + 2 * NBP, aB0, aB1, aB2, aB3);
        }

        L0(bxA, buf, 0);
        L0(bxB, buf, 1);
        AGG(buf, 0);
        AGG(buf, 1);

        asm volatile("s_waitcnt lgkmcnt(0)" ::: "memory");
        __builtin_amdgcn_s_barrier();          // zB/aggP[buf] (both streams) ready

        CONSUME(buf, 0, nA);
        CONSUME(buf, 1, nB);
        // no trailing barrier: iter k+2 reuses this buf, and every wave passes iter
        // k+1's barrier only after consuming (hence completing) iter k's reads.
    }

    if (STATS) {
        // disjoint cols across waves -> single staging array, one coalesced store
#pragma unroll
        for (int njl = 0; njl < 2; njl++) {
            float s = as_[njl];
            s += __shfl_xor(s, 16); s += __shfl_xor(s, 32);
            float qq = aq[njl];
            qq += __shfl_xor(qq, 16); qq += __shfl_xor(qq, 32);
            if (l < 16) {
                int col = 32 * w + 16 * njl + l;
                pbuf[col] = s;
                pbuf[128 + col] = qq;
            }
        }
        __syncthreads();
        pout[(size_t)blockIdx.x * 256 + t] = pbuf[t];
    }
}

extern "C" void kernel_launch(void* const* d_in, const int* in_sizes, int n_in,
                              void* d_out, int out_size, void* d_ws, size_t ws_size,
                              hipStream_t stream) {
    (void)in_sizes; (void)n_in; (void)out_size; (void)ws_size;
    const float* x      = (const float*)d_in[0];
    const float* W0     = (const float*)d_in[1];
    const float* gamma0 = (const float*)d_in[2];
    const float* beta0  = (const float*)d_in[3];
    const float* W1     = (const float*)d_in[4];
    const float* gamma1 = (const float*)d_in[5];
    const float* beta1  = (const float*)d_in[6];
    float* out = (float*)d_out;
    float* ws  = (float*)d_ws;

    k_stats0<<<NB0, 256, 0, stream>>>(x, out);                       // partials -> out
    k_finalize0<<<1, 256, 0, stream>>>(out, ws, W0, gamma0, beta0);
    k_pass<true><<<NBP, 256, 0, stream>>>(x, W0, W1, ws, out);       // partials -> out
    k_finalize1<<<128, 256, 0, stream>>>(out, ws, gamma1, beta1);
    k_pass<false><<<NBP, 256, 0, stream>>>(x, W0, W1, ws, out);      // final output
}